// Round 6
// baseline (4837.527 us; speedup 1.0000x reference)
//
#include <hip/hip_runtime.h>
#include <math.h>

#define T_SEQ 256
#define BATCH 128
#define HID 512
#define NL 4
// d_out: out [128][256][768] fp32 | hT [4][128][512] | cT [4][128][512]
#define HT_OFF 25165824u
#define CT_OFF 25427968u
// ws: h_all bf16 [4][257][128][512] | xp bf16 [256][128][512] | flags [4][256][64]
// h_all tile layout (granule-interleaved): elem (row,k) at ((k>>2)*128+row)*4+(k&3)
// xp layout: [t][b][n] row-major (also receives layer-3 h for gemm_out)
#define HALL_ELEMS 67371008u
#define XP_ELEMS   16777216u
#define FLG_OFF(l,t) ((((l) << 8) + (t)) << 6)   // 64 dwords per (l,t); counters at dwords 0,16,32,48

typedef __attribute__((ext_vector_type(8))) short bf16x8;
typedef __attribute__((ext_vector_type(4))) float f32x4;

#define GSTR 35                                   // gates LDS row stride (bank-spread)
#define WGSC __HIP_MEMORY_SCOPE_WORKGROUP

__device__ __forceinline__ short f2bf(float f) {
    unsigned u = __float_as_uint(f);
    u = (u + 0x7fffu + ((u >> 16) & 1u)) >> 16;
    return (short)u;
}
__device__ __forceinline__ unsigned pack2(float a, float b) {
    return ((unsigned)(unsigned short)f2bf(a)) |
           (((unsigned)(unsigned short)f2bf(b)) << 16);
}
// race-exposed load: 16B fragment via two 8B agent-scope atomic loads (bypass
// stale L1/L2 -> LLC coherence point). Granule layout: halves 512 shorts apart;
// 16 lanes at consecutive rows -> 4 fully-consumed 128B lines per inst.
__device__ __forceinline__ bf16x8 ld8_sc1g(const short* p) {
    unsigned long long q0 = __hip_atomic_load((const unsigned long long*)p,
                                              __ATOMIC_RELAXED, __HIP_MEMORY_SCOPE_AGENT);
    unsigned long long q1 = __hip_atomic_load((const unsigned long long*)(p + 512),
                                              __ATOMIC_RELAXED, __HIP_MEMORY_SCOPE_AGENT);
    union { unsigned long long q[2]; bf16x8 v; } u;
    u.q[0] = q0; u.q[1] = q1;
    return u.v;
}
// single-wave poll of the 4 arrival counters (16 blocks x 4 h-waves = 64 each)
__device__ __forceinline__ void poll_cnt4(const unsigned* base, int lane) {
    const unsigned* p = base + ((lane & 3) << 4);   // 4 counters, 64B apart
    unsigned v = __hip_atomic_load(p, __ATOMIC_RELAXED, __HIP_MEMORY_SCOPE_AGENT);
    while (__any(v < 64u)) {
        __builtin_amdgcn_s_sleep(1);
        v = __hip_atomic_load(p, __ATOMIC_RELAXED, __HIP_MEMORY_SCOPE_AGENT);
    }
    asm volatile("" ::: "memory");                  // poll completes before publish
}
// LDS progress waits: acquire pairs with producers' release add/store
__device__ __forceinline__ void spin_ge(int* p, int want) {          // tight
    while (__hip_atomic_load(p, __ATOMIC_ACQUIRE, WGSC) < want) {}
    asm volatile("" ::: "memory");
}
__device__ __forceinline__ void spin_ge_sleep(int* p, int want) {    // long-wait
    while (__hip_atomic_load(p, __ATOMIC_ACQUIRE, WGSC) < want)
        __builtin_amdgcn_s_sleep(1);
    asm volatile("" ::: "memory");
}
// stable tanh via exp: tanh(x)=sign(x)*(1-t)/(1+t), t=e^{-2|x|}
__device__ __forceinline__ float tanh_fast(float x) {
    float t = __expf(-2.f * fabsf(x));
    return copysignf((1.f - t) / (1.f + t), x);
}

// ---------------------------------------------------------------------------
__global__ void init_kernel(short* __restrict__ h_all, unsigned* __restrict__ flg,
                            const float* __restrict__ h0) {
    int idx = blockIdx.x * 256 + threadIdx.x;       // grid 1024*256
    if (idx < NL * BATCH * HID) {
        int l = idx >> 16, rest = idx & 65535;
        int r = rest >> 9, k = rest & 511;
        h_all[((size_t)(l * 257) << 16) + (((size_t)(k >> 2)) << 9) + (r << 2) + (k & 3)]
            = f2bf(h0[idx]);
    }
    if (idx < NL * T_SEQ * 64) flg[idx] = 0u;
}

// ---------------------------------------------------------------------------
// xp-GEMM: xp[t][b][n] (bf16) = x[b][t][:768] @ W_in[n][:768] + b_in[n]
// ---------------------------------------------------------------------------
__global__ __launch_bounds__(256) void gemm_xp(const float* __restrict__ x,
                                               const float* __restrict__ W_in,
                                               const float* __restrict__ b_in,
                                               short* __restrict__ xp) {
    __shared__ short As[128 * 72];
    __shared__ short Bs[128 * 72];
    const int tid = threadIdx.x;
    const int w = tid >> 6, lane = tid & 63;
    const int m = lane & 15, quad = lane >> 4;
    const int rowbase = blockIdx.x * 128;           // M = 32768 (b*256+t)
    const int colbase = blockIdx.y * 128;           // N = 512
    f32x4 acc[2][8];
#pragma unroll
    for (int rt = 0; rt < 2; ++rt)
#pragma unroll
        for (int ct = 0; ct < 8; ++ct) { f32x4 z = {0.f,0.f,0.f,0.f}; acc[rt][ct] = z; }

    for (int k0 = 0; k0 < 768; k0 += 64) {
        __syncthreads();
#pragma unroll
        for (int i = 0; i < 8; ++i) {
            int q = tid + (i << 8);
            int r = q >> 4, f4 = (q & 15) << 2;
            float4 v = *(const float4*)(x + (size_t)(rowbase + r) * 768 + k0 + f4);
            uint2 p; p.x = pack2(v.x, v.y); p.y = pack2(v.z, v.w);
            *(uint2*)&As[r * 72 + f4] = p;
        }
#pragma unroll
        for (int i = 0; i < 8; ++i) {
            int q = tid + (i << 8);
            int r = q >> 4, f4 = (q & 15) << 2;
            float4 v = *(const float4*)(W_in + (size_t)(colbase + r) * 768 + k0 + f4);
            uint2 p; p.x = pack2(v.x, v.y); p.y = pack2(v.z, v.w);
            *(uint2*)&Bs[r * 72 + f4] = p;
        }
        __syncthreads();
#pragma unroll
        for (int ks = 0; ks < 2; ++ks) {
            int kof = (ks << 5) + (quad << 3);
            bf16x8 a0 = *(const bf16x8*)&As[((w * 2 + 0) * 16 + m) * 72 + kof];
            bf16x8 a1 = *(const bf16x8*)&As[((w * 2 + 1) * 16 + m) * 72 + kof];
#pragma unroll
            for (int ct = 0; ct < 8; ++ct) {
                bf16x8 b = *(const bf16x8*)&Bs[(ct * 16 + m) * 72 + kof];
                acc[0][ct] = __builtin_amdgcn_mfma_f32_16x16x32_bf16(a0, b, acc[0][ct], 0, 0, 0);
                acc[1][ct] = __builtin_amdgcn_mfma_f32_16x16x32_bf16(a1, b, acc[1][ct], 0, 0, 0);
            }
        }
    }
    float bias_r[8];
#pragma unroll
    for (int ct = 0; ct < 8; ++ct) bias_r[ct] = b_in[colbase + ct * 16 + m];
#pragma unroll
    for (int rt = 0; rt < 2; ++rt)
#pragma unroll
        for (int reg = 0; reg < 4; ++reg) {
            int m_glob = rowbase + (w * 2 + rt) * 16 + quad * 4 + reg;
            int t = m_glob & 255, b = m_glob >> 8;
            short* dst = xp + (((size_t)(t << 7) + b) << 9);
#pragma unroll
            for (int ct = 0; ct < 8; ++ct)
                dst[colbase + ct * 16 + m] = f2bf(acc[rt][ct][reg] + bias_r[ct]);
        }
}

// ---------------------------------------------------------------------------
// out-GEMM: out[b][t][n] (fp32) = h3[t][b][:512] @ W_out[n][:512] + b_out[n]
// h3 comes from the xp buffer ([t][b][n] layout, dual-written by layer 3).
// ---------------------------------------------------------------------------
__global__ __launch_bounds__(256) void gemm_out(const short* __restrict__ h3,
                                                const float* __restrict__ W_out,
                                                const float* __restrict__ b_out,
                                                float* __restrict__ out) {
    __shared__ short As[128 * 72];
    __shared__ short Bs[128 * 72];
    const int tid = threadIdx.x;
    const int w = tid >> 6, lane = tid & 63;
    const int m = lane & 15, quad = lane >> 4;
    const int rowbase = blockIdx.x * 128;           // M = 32768 (t*128+b)
    const int colbase = blockIdx.y * 128;           // N = 768
    f32x4 acc[2][8];
#pragma unroll
    for (int rt = 0; rt < 2; ++rt)
#pragma unroll
        for (int ct = 0; ct < 8; ++ct) { f32x4 z = {0.f,0.f,0.f,0.f}; acc[rt][ct] = z; }

    for (int k0 = 0; k0 < 512; k0 += 64) {
        __syncthreads();
#pragma unroll
        for (int i = 0; i < 4; ++i) {
            int q = tid + (i << 8);
            int r = q >> 3, seg = (q & 7) << 3;
            *(bf16x8*)&As[r * 72 + seg] =
                *(const bf16x8*)(h3 + (size_t)(rowbase + r) * 512 + k0 + seg);
        }
#pragma unroll
        for (int i = 0; i < 8; ++i) {
            int q = tid + (i << 8);
            int r = q >> 4, f4 = (q & 15) << 2;
            float4 v = *(const float4*)(W_out + (size_t)(colbase + r) * 512 + k0 + f4);
            uint2 p; p.x = pack2(v.x, v.y); p.y = pack2(v.z, v.w);
            *(uint2*)&Bs[r * 72 + f4] = p;
        }
        __syncthreads();
#pragma unroll
        for (int ks = 0; ks < 2; ++ks) {
            int kof = (ks << 5) + (quad << 3);
            bf16x8 a0 = *(const bf16x8*)&As[((w * 2 + 0) * 16 + m) * 72 + kof];
            bf16x8 a1 = *(const bf16x8*)&As[((w * 2 + 1) * 16 + m) * 72 + kof];
#pragma unroll
            for (int ct = 0; ct < 8; ++ct) {
                bf16x8 b = *(const bf16x8*)&Bs[(ct * 16 + m) * 72 + kof];
                acc[0][ct] = __builtin_amdgcn_mfma_f32_16x16x32_bf16(a0, b, acc[0][ct], 0, 0, 0);
                acc[1][ct] = __builtin_amdgcn_mfma_f32_16x16x32_bf16(a1, b, acc[1][ct], 0, 0, 0);
            }
        }
    }
    float bias_r[8];
#pragma unroll
    for (int ct = 0; ct < 8; ++ct) bias_r[ct] = b_out[colbase + ct * 16 + m];
#pragma unroll
    for (int rt = 0; rt < 2; ++rt)
#pragma unroll
        for (int reg = 0; reg < 4; ++reg) {
            int m_glob = rowbase + (w * 2 + rt) * 16 + quad * 4 + reg;
            int t = m_glob >> 7, b = m_glob & 127;
            float* dst = out + (size_t)b * 196608 + (size_t)t * 768;
#pragma unroll
            for (int ct = 0; ct < 8; ++ct)
                dst[colbase + ct * 16 + m] = acc[rt][ct][reg] + bias_r[ct];
        }
}

// ---------------------------------------------------------------------------
// Persistent MFMA LSTM pipeline. 256 blocks = 4 layers x 64 col-chunks,
// 512 thr = 8 waves. v6: DECOUPLED wave-groups, no __syncthreads in loop.
//  x-group (waves 0-3, W_ih): computes gatesX[t&1] (double-buffered), runs
//    up to 2 steps ahead (bounded by hb2). Signals per-wave via xb counter.
//  h-group (waves 4-7, W_hh): the recurrence. poll flag(l,t-1) -> sc1 loads
//    -> MFMA -> hb1 4-wave barrier -> wait xb -> elementwise (4 cells/thr)
//    -> sc1 h stores -> per-wave vmcnt(0) -> per-wave flag RMW (+1, target
//    64 = 16 blocks x 4 waves) -> hb2 add. setprio(1) on h-waves (T5).
// Memory model unchanged from v4/v5: granule-interleaved h tiles, sc1
// stores/loads at agent scope, 4 flag counters per (l,t) 64B apart.
// ---------------------------------------------------------------------------
#define LOADQ(A0_, A1_, kb_)                                                  \
    _Pragma("unroll")                                                         \
    for (int kk = 0; kk < 4; ++kk) {                                          \
        int ks = (kb_) * 4 + kk;                                              \
        int g = ks * 8 + quad * 2;                                            \
        const short* pq = src + ((size_t)g << 9) + ((w2 * 32 + m) << 2);      \
        A0_[kk] = ld8_sc1g(pq);                                               \
        A1_[kk] = ld8_sc1g(pq + 64);                                          \
    }
#define COMPQ(A0_, A1_, kb_)                                                  \
    _Pragma("unroll")                                                         \
    for (int kk = 0; kk < 4; ++kk) {                                          \
        int ks = (kb_) * 4 + kk;                                              \
        acc00 = __builtin_amdgcn_mfma_f32_16x16x32_bf16(A0_[kk], wf[ks*2+0], acc00, 0, 0, 0); \
        acc01 = __builtin_amdgcn_mfma_f32_16x16x32_bf16(A0_[kk], wf[ks*2+1], acc01, 0, 0, 0); \
        acc10 = __builtin_amdgcn_mfma_f32_16x16x32_bf16(A1_[kk], wf[ks*2+0], acc10, 0, 0, 0); \
        acc11 = __builtin_amdgcn_mfma_f32_16x16x32_bf16(A1_[kk], wf[ks*2+1], acc11, 0, 0, 0); \
    }
#define GWRITE(gdst_)                                                         \
    _Pragma("unroll")                                                         \
    for (int reg = 0; reg < 4; ++reg) {                                       \
        (gdst_)[(gb0 + reg) * GSTR + m]           = acc00[reg];               \
        (gdst_)[(gb0 + reg) * GSTR + 16 + m]      = acc01[reg];               \
        (gdst_)[(gb0 + 16 + reg) * GSTR + m]      = acc10[reg];               \
        (gdst_)[(gb0 + 16 + reg) * GSTR + 16 + m] = acc11[reg];               \
    }

__global__ __launch_bounds__(512, 1) void lstm_pipeline(
    short* __restrict__ xp, short* __restrict__ h_all,
    unsigned* __restrict__ flg,
    const float* __restrict__ W_ih, const float* __restrict__ W_hh,
    const float* __restrict__ b_ih, const float* __restrict__ b_hh,
    const float* __restrict__ c0, float* __restrict__ d_out) {
    __shared__ float gatesX[2][128 * GSTR];
    __shared__ float gatesH[128 * GSTR];
    __shared__ float cL[128 * 9];
    __shared__ float biasL[32];
    __shared__ int ldsdep[2];          // [0]: x-dep publish, [1]: h-dep publish
    __shared__ int xb, hb1, hb2;       // monotonic arrival counters (1/wave/step)

    const int tid = threadIdx.x;
    const int l = blockIdx.x >> 6, c = blockIdx.x & 63;
    const int w = tid >> 6, lane = tid & 63;
    const int m = lane & 15, quad = lane >> 4;
    const bool hw = (w >= 4);
    const int w2 = w & 3;

    // --- load weight fragments into registers (once) ---
    const float* Wsrc = hw ? W_hh : W_ih;
    bf16x8 wf[32];
#pragma unroll
    for (int ks = 0; ks < 16; ++ks) {
#pragma unroll
        for (int ct = 0; ct < 2; ++ct) {
            int u = ct * 16 + m;
            int gr = ((u >> 3) << 9) + (c << 3) + (u & 7);
            const float* s = Wsrc + ((size_t)(l * 2048 + gr) << 9) + ks * 32 + quad * 8;
            float4 v0 = *(const float4*)s;
            float4 v1 = *(const float4*)(s + 4);
            uint4 p;
            p.x = pack2(v0.x, v0.y); p.y = pack2(v0.z, v0.w);
            p.z = pack2(v1.x, v1.y); p.w = pack2(v1.z, v1.w);
            wf[ks * 2 + ct] = *(bf16x8*)&p;
        }
    }
    if (tid < 32) {
        int gr = ((tid >> 3) << 9) + (c << 3) + (tid & 7);
        biasL[tid] = b_ih[l * 2048 + gr] + b_hh[l * 2048 + gr];
    }
    if (tid < 2) ldsdep[tid] = 0;
    if (tid == 2) { xb = 0; }
    if (tid == 3) { hb1 = 0; }
    if (tid == 4) { hb2 = 0; }
    for (int p = tid; p < 1024; p += 512) {
        int r = p >> 3, hc = p & 7;
        cL[r * 9 + hc] = c0[((size_t)l << 16) + (r << 9) + (c << 3) + hc];
    }
    __syncthreads();

    if (!hw) {
        // ================= x-group: one step ahead =================
        for (int t = 0; t < T_SEQ; ++t) {
            if (l > 0) {
                if (w == 0) {
                    poll_cnt4(flg + FLG_OFF(l - 1, t), lane);
                    __hip_atomic_store(&ldsdep[0], t + 1, __ATOMIC_RELEASE, WGSC);
                } else {
                    spin_ge_sleep(&ldsdep[0], t + 1);
                }
            }
            f32x4 z = {0.f, 0.f, 0.f, 0.f};
            f32x4 acc00 = z, acc01 = z, acc10 = z, acc11 = z;
            if (l == 0) {
                const short* src = xp + ((size_t)t << 16);
#pragma unroll
                for (int ks = 0; ks < 16; ++ks) {
                    int ka = ks * 32 + quad * 8;
                    bf16x8 a0 = *(const bf16x8*)(src + ((size_t)(w2 * 32 + m) << 9) + ka);
                    bf16x8 a1 = *(const bf16x8*)(src + ((size_t)(w2 * 32 + 16 + m) << 9) + ka);
                    acc00 = __builtin_amdgcn_mfma_f32_16x16x32_bf16(a0, wf[ks * 2 + 0], acc00, 0, 0, 0);
                    acc01 = __builtin_amdgcn_mfma_f32_16x16x32_bf16(a0, wf[ks * 2 + 1], acc01, 0, 0, 0);
                    acc10 = __builtin_amdgcn_mfma_f32_16x16x32_bf16(a1, wf[ks * 2 + 0], acc10, 0, 0, 0);
                    acc11 = __builtin_amdgcn_mfma_f32_16x16x32_bf16(a1, wf[ks * 2 + 1], acc11, 0, 0, 0);
                }
            } else {
                const short* src = h_all + ((size_t)((l - 1) * 257 + t + 1) << 16);
                bf16x8 Pa[4], Pb[4], Qa[4], Qb[4];
                LOADQ(Pa, Pb, 0)
                LOADQ(Qa, Qb, 1)
                COMPQ(Pa, Pb, 0)
                LOADQ(Pa, Pb, 2)
                COMPQ(Qa, Qb, 1)
                LOADQ(Qa, Qb, 3)
                COMPQ(Pa, Pb, 2)
                COMPQ(Qa, Qb, 3)
            }
            // wait until gatesX[t&1] is free (h elementwise of step t-2 done)
            if (t >= 2) spin_ge_sleep(&hb2, 4 * (t - 1));
            float* gX = gatesX[t & 1];
            const int gb0 = w2 * 32 + quad * 4;
            GWRITE(gX)
            if (lane == 0)
                __hip_atomic_fetch_add(&xb, 1, __ATOMIC_ACQ_REL, WGSC);
        }
    } else {
        // ================= h-group: the recurrence =================
        __builtin_amdgcn_s_setprio(1);
        const int ht = tid - 256, er = ht >> 1, eq0 = (ht & 1) * 4;
        for (int t = 0; t < T_SEQ; ++t) {
            if (t > 0) {
                if (w == 4) {
                    poll_cnt4(flg + FLG_OFF(l, t - 1), lane);
                    __hip_atomic_store(&ldsdep[1], t, __ATOMIC_RELEASE, WGSC);
                } else {
                    spin_ge_sleep(&ldsdep[1], t);
                }
            }
            f32x4 z = {0.f, 0.f, 0.f, 0.f};
            f32x4 acc00 = z, acc01 = z, acc10 = z, acc11 = z;
            {
                const short* src = h_all + ((size_t)(l * 257 + t) << 16);
                bf16x8 Pa[4], Pb[4], Qa[4], Qb[4];
                LOADQ(Pa, Pb, 0)
                LOADQ(Qa, Qb, 1)
                COMPQ(Pa, Pb, 0)
                LOADQ(Pa, Pb, 2)
                COMPQ(Qa, Qb, 1)
                LOADQ(Qa, Qb, 3)
                COMPQ(Pa, Pb, 2)
                COMPQ(Qa, Qb, 3)
            }
            const int gb0 = w2 * 32 + quad * 4;
            GWRITE(gatesH)
            if (lane == 0)
                __hip_atomic_fetch_add(&hb1, 1, __ATOMIC_ACQ_REL, WGSC);
            spin_ge(&hb1, 4 * (t + 1));            // gatesH complete (4 h-waves)
            spin_ge(&xb, 4 * (t + 1));             // gatesX[t&1] complete
            const float* gX = gatesX[t & 1];

            // --- elementwise: 4 adjacent cells per thread ---
            float hv[4], cv[4];
#pragma unroll
            for (int e = 0; e < 4; ++e) {
                int hc = eq0 + e;
                float iv = gX[er * GSTR + hc]      + gatesH[er * GSTR + hc]      + biasL[hc];
                float fv = gX[er * GSTR + 8 + hc]  + gatesH[er * GSTR + 8 + hc]  + biasL[8 + hc];
                float gv = gX[er * GSTR + 16 + hc] + gatesH[er * GSTR + 16 + hc] + biasL[16 + hc];
                float ov = gX[er * GSTR + 24 + hc] + gatesH[er * GSTR + 24 + hc] + biasL[24 + hc];
                float ig = 1.f / (1.f + __expf(-iv));
                float fg = 1.f / (1.f + __expf(-fv));
                float gg = tanh_fast(gv);
                float og = 1.f / (1.f + __expf(-ov));
                float cn = fg * cL[er * 9 + hc] + ig * gg;
                float hn = og * tanh_fast(cn);
                cL[er * 9 + hc] = cn;
                hv[e] = hn; cv[e] = cn;
            }
            unsigned long long pk;
            {
                union { unsigned u[2]; unsigned long long q; } uu;
                uu.u[0] = pack2(hv[0], hv[1]); uu.u[1] = pack2(hv[2], hv[3]);
                pk = uu.q;
            }
            // granule store: cells are shorts [er*4 .. +3] of granule 2c+(ht&1)
            {
                int g = c * 2 + (ht & 1);
                unsigned long long* hdst =
                    (unsigned long long*)(h_all + ((size_t)(l * 257 + t + 1) << 16)
                                          + ((size_t)g << 9) + (er << 2));
                __hip_atomic_store(hdst, pk, __ATOMIC_RELAXED, __HIP_MEMORY_SCOPE_AGENT);
            }
            if (l == 3) {
                unsigned long long* xdst =
                    (unsigned long long*)(xp + ((size_t)t << 16) + (er << 9) + (c << 3) + eq0);
                __hip_atomic_store(xdst, pk, __ATOMIC_RELAXED, __HIP_MEMORY_SCOPE_AGENT);
            }
            if (t == T_SEQ - 1) {
                size_t fo = ((size_t)l << 16) + (size_t)(er << 9) + (c << 3) + eq0;
                *(float4*)(d_out + HT_OFF + fo) = make_float4(hv[0], hv[1], hv[2], hv[3]);
                *(float4*)(d_out + CT_OFF + fo) = make_float4(cv[0], cv[1], cv[2], cv[3]);
            }
            asm volatile("s_waitcnt vmcnt(0)" ::: "memory");  // own stores at LLC
            if (lane == 0) {
                __hip_atomic_fetch_add(flg + FLG_OFF(l, t) + ((c >> 4) << 4), 1u,
                                       __ATOMIC_RELAXED, __HIP_MEMORY_SCOPE_AGENT);
                __hip_atomic_fetch_add(&hb2, 1, __ATOMIC_RELEASE, WGSC);
            }
        }
    }
}

// ---------------------------------------------------------------------------
__global__ __launch_bounds__(256) void ln_kernel(float* __restrict__ out,
                                                 const float* __restrict__ g,
                                                 const float* __restrict__ bvec) {
    float* p = out + (size_t)blockIdx.x * 768;
    int tid = threadIdx.x;
    float v0 = p[tid], v1 = p[tid + 256], v2 = p[tid + 512];
    float s = v0 + v1 + v2;
    float q = v0 * v0 + v1 * v1 + v2 * v2;
    for (int off = 32; off > 0; off >>= 1) {
        s += __shfl_down(s, off);
        q += __shfl_down(q, off);
    }
    __shared__ float ss[4], qq[4];
    __shared__ float mu_s, rs_s;
    int w = tid >> 6;
    if ((tid & 63) == 0) { ss[w] = s; qq[w] = q; }
    __syncthreads();
    if (tid == 0) {
        float S = ss[0] + ss[1] + ss[2] + ss[3];
        float Q = qq[0] + qq[1] + qq[2] + qq[3];
        float mu = S * (1.f / 768.f);
        float var = Q * (1.f / 768.f) - mu * mu;
        mu_s = mu;
        rs_s = rsqrtf(var + 1e-5f);
    }
    __syncthreads();
    float mu = mu_s, rs = rs_s;
    p[tid]       = (v0 - mu) * rs * g[tid]       + bvec[tid];
    p[tid + 256] = (v1 - mu) * rs * g[tid + 256] + bvec[tid + 256];
    p[tid + 512] = (v2 - mu) * rs * g[tid + 512] + bvec[tid + 512];
}

// ---------------------------------------------------------------------------
extern "C" void kernel_launch(void* const* d_in, const int* in_sizes, int n_in,
                              void* d_out, int out_size, void* d_ws, size_t ws_size,
                              hipStream_t stream) {
    (void)in_sizes; (void)n_in; (void)out_size; (void)ws_size;
    const float* x     = (const float*)d_in[0];
    const float* h0    = (const float*)d_in[1];
    const float* c0    = (const float*)d_in[2];
    const float* W_in  = (const float*)d_in[3];
    const float* b_in  = (const float*)d_in[4];
    const float* W_ih  = (const float*)d_in[5];
    const float* W_hh  = (const float*)d_in[6];
    const float* b_ih  = (const float*)d_in[7];
    const float* b_hh  = (const float*)d_in[8];
    const float* W_out = (const float*)d_in[9];
    const float* b_out = (const float*)d_in[10];
    const float* ln_g  = (const float*)d_in[11];
    const float* ln_b  = (const float*)d_in[12];

    float* out   = (float*)d_out;
    short* h_all = (short*)d_ws;
    short* xp    = h_all + HALL_ELEMS;
    unsigned* flg = (unsigned*)(xp + XP_ELEMS);

    init_kernel<<<1024, 256, 0, stream>>>(h_all, flg, h0);
    gemm_xp<<<dim3(256, 4), 256, 0, stream>>>(x, W_in, b_in, xp);
    lstm_pipeline<<<256, 512, 0, stream>>>(xp, h_all, flg, W_ih, W_hh,
                                           b_ih, b_hh, c0, out);
    gemm_out<<<dim3(256, 6), 256, 0, stream>>>(xp, W_out, b_out, out);
    ln_kernel<<<32768, 256, 0, stream>>>(out, ln_g, ln_b);
}